// Round 1
// baseline (644.820 us; speedup 1.0000x reference)
//
#include <hip/hip_runtime.h>

// Boids ODE message-passing:
//   per edge e: i=dst[e], j=src[e]
//   dp = pos[j]-pos[i]; dv = vel[j]-vel[i]; params = p_table[ptype[i]]
//   d2 = dot(dp,dp); sd2 = d2>0 ? d2 : 1
//   msg = (p0*A1*dp + p1*A2*dv - p2*A3*dp/sd2) * field[j]
//   out[i] += msg   (segment_sum over dst)

#define BOIDS_A1 5e-06f
#define BOIDS_A2 0.0005f
#define BOIDS_A3 1e-08f

__global__ void boids_edge_kernel(const float* __restrict__ pos,
                                  const float* __restrict__ vel,
                                  const float* __restrict__ p_table,
                                  const float* __restrict__ field,
                                  const int* __restrict__ ptype,
                                  const int* __restrict__ dst_idx,
                                  const int* __restrict__ src_idx,
                                  float* __restrict__ out,
                                  int n_edges) {
    int e = blockIdx.x * blockDim.x + threadIdx.x;
    if (e >= n_edges) return;

    int i = dst_idx[e];   // receiver
    int j = src_idx[e];   // sender

    float2 pi = *reinterpret_cast<const float2*>(pos + 2 * i);
    float2 pj = *reinterpret_cast<const float2*>(pos + 2 * j);
    float2 vi = *reinterpret_cast<const float2*>(vel + 2 * i);
    float2 vj = *reinterpret_cast<const float2*>(vel + 2 * j);

    float dpx = pj.x - pi.x;
    float dpy = pj.y - pi.y;
    float dvx = vj.x - vi.x;
    float dvy = vj.y - vi.y;

    int t = ptype[i];
    float p0 = p_table[3 * t + 0];
    float p1 = p_table[3 * t + 1];
    float p2 = p_table[3 * t + 2];

    float d2 = dpx * dpx + dpy * dpy;
    float sd2 = (d2 > 0.0f) ? d2 : 1.0f;

    // msg = (p0*A1 - p2*A3/sd2) * dp + (p1*A2) * dv, all scaled by field[j]
    float coef_dp = p0 * BOIDS_A1 - p2 * BOIDS_A3 / sd2;
    float coef_dv = p1 * BOIDS_A2;
    float f = field[j];

    float mx = (coef_dp * dpx + coef_dv * dvx) * f;
    float my = (coef_dp * dpy + coef_dv * dvy) * f;

    atomicAdd(&out[2 * i + 0], mx);
    atomicAdd(&out[2 * i + 1], my);
}

extern "C" void kernel_launch(void* const* d_in, const int* in_sizes, int n_in,
                              void* d_out, int out_size, void* d_ws, size_t ws_size,
                              hipStream_t stream) {
    const float* pos     = (const float*)d_in[0];   // [N,2]
    const float* vel     = (const float*)d_in[1];   // [N,2]
    const float* p_table = (const float*)d_in[2];   // [16,3]
    const float* field   = (const float*)d_in[3];   // [N,1]
    const int*   ptype   = (const int*)d_in[4];     // [N]
    const int*   eidx    = (const int*)d_in[5];     // [2,E]: row0=dst, row1=src

    int n_edges = in_sizes[5] / 2;
    const int* dst_idx = eidx;
    const int* src_idx = eidx + n_edges;

    float* out = (float*)d_out;

    // d_out is poisoned (0xAA) before timing and not re-poisoned between
    // replays; we accumulate with atomics, so zero it every call.
    hipMemsetAsync(out, 0, (size_t)out_size * sizeof(float), stream);

    int block = 256;
    int grid = (n_edges + block - 1) / block;
    boids_edge_kernel<<<grid, block, 0, stream>>>(pos, vel, p_table, field,
                                                  ptype, dst_idx, src_idx,
                                                  out, n_edges);
}

// Round 2
// 213.604 us; speedup vs baseline: 3.0188x; 3.0188x over previous
//
#include <hip/hip_runtime.h>

// Boids ODE segment-sum, atomic-free via bucketed counting sort.
//   bucket = dst >> 7  (128 receiver nodes per bucket)
//   K1 count -> K2 scan(3 kernels) -> K3 scatter pairs -> K4 accumulate in LDS

#define BA1 5e-06f
#define BA2 0.0005f
#define BA3 1e-08f

#define NT 256        // threads for count/scatter/accum kernels
#define EPB 8192      // edges per count/scatter block
#define WIN 128       // receiver nodes per bucket (dst >> 7)
#define SCAN_T 1024   // scan block width

// ---------------- K1: per-block bucket histogram ----------------
__global__ void k_count(const int* __restrict__ dst, int E, int NB, int NBLK,
                        unsigned* __restrict__ C) {
    extern __shared__ unsigned hist[];   // NB entries
    int blk = blockIdx.x, tid = threadIdx.x;
    for (int b = tid; b < NB; b += NT) hist[b] = 0u;
    __syncthreads();
    int s = blk * EPB, e = min(E, s + EPB);
    for (int k = s + tid; k < e; k += NT) {
        atomicAdd(&hist[dst[k] >> 7], 1u);   // LDS atomic
    }
    __syncthreads();
    for (int b = tid; b < NB; b += NT) C[(size_t)b * NBLK + blk] = hist[b];
}

// ---------------- K2: exclusive scan (in-place, two-level) ----------------
__global__ void k_scan(unsigned* __restrict__ data, unsigned* __restrict__ sums, int M) {
    __shared__ unsigned tmp[SCAN_T];
    int tid = threadIdx.x;
    int gid = blockIdx.x * SCAN_T + tid;
    unsigned v = (gid < M) ? data[gid] : 0u;
    tmp[tid] = v;
    __syncthreads();
    for (int o = 1; o < SCAN_T; o <<= 1) {
        unsigned t = (tid >= o) ? tmp[tid - o] : 0u;
        __syncthreads();
        tmp[tid] += t;
        __syncthreads();
    }
    if (gid < M) data[gid] = tmp[tid] - v;                   // exclusive
    if (sums != nullptr && tid == SCAN_T - 1) sums[blockIdx.x] = tmp[tid];
}

__global__ void k_scan_add(unsigned* __restrict__ data,
                           const unsigned* __restrict__ sums, int M) {
    int gid = blockIdx.x * SCAN_T + threadIdx.x;
    if (gid < M) data[gid] += sums[blockIdx.x];
}

// ---------------- K3: scatter (dst,src) pairs into bucket regions ----------------
__global__ void k_scatter(const int* __restrict__ dst, const int* __restrict__ src,
                          int E, int NB, int NBLK,
                          const unsigned* __restrict__ off,
                          uint2* __restrict__ pairs) {
    extern __shared__ unsigned cur[];    // NB cursors
    int blk = blockIdx.x, tid = threadIdx.x;
    for (int b = tid; b < NB; b += NT) cur[b] = off[(size_t)b * NBLK + blk];
    __syncthreads();
    int s = blk * EPB, e = min(E, s + EPB);
    for (int k = s + tid; k < e; k += NT) {
        int d = dst[k];
        unsigned p = atomicAdd(&cur[d >> 7], 1u);  // LDS atomic w/ return
        pairs[p] = make_uint2((unsigned)d, (unsigned)src[k]);
    }
}

// ---------------- K4: per-bucket accumulate in LDS, write out ----------------
__global__ void k_accum(const float* __restrict__ pos, const float* __restrict__ vel,
                        const float* __restrict__ p_table, const float* __restrict__ field,
                        const int* __restrict__ ptype,
                        const uint2* __restrict__ pairs,
                        const unsigned* __restrict__ off,
                        int E, int N, int NB, int NBLK,
                        float* __restrict__ out) {
    __shared__ float wpx[WIN], wpy[WIN], wvx[WIN], wvy[WIN];
    __shared__ float wc0[WIN], wc1[WIN], wc2[WIN];
    __shared__ float acc[2 * WIN];
    int b = blockIdx.x, tid = threadIdx.x;
    int base = b * WIN;
    int wn = min(N - base, WIN);

    for (int t = tid; t < wn; t += NT) {
        int g = base + t;
        float2 p = *reinterpret_cast<const float2*>(pos + 2 * g);
        float2 v = *reinterpret_cast<const float2*>(vel + 2 * g);
        wpx[t] = p.x; wpy[t] = p.y; wvx[t] = v.x; wvy[t] = v.y;
        int ty = ptype[g];
        wc0[t] = p_table[3 * ty + 0] * BA1;
        wc1[t] = p_table[3 * ty + 1] * BA2;
        wc2[t] = p_table[3 * ty + 2] * BA3;
    }
    for (int t = tid; t < 2 * WIN; t += NT) acc[t] = 0.f;
    __syncthreads();

    unsigned s = off[(size_t)b * NBLK];
    unsigned e = (b + 1 < NB) ? off[(size_t)(b + 1) * NBLK] : (unsigned)E;
    for (unsigned k = s + tid; k < e; k += NT) {
        uint2 pr = pairs[k];
        int i = (int)pr.x, j = (int)pr.y;
        int l = i - base;
        float2 pj = *reinterpret_cast<const float2*>(pos + 2 * j);
        float2 vj = *reinterpret_cast<const float2*>(vel + 2 * j);
        float f = field[j];
        float dpx = pj.x - wpx[l], dpy = pj.y - wpy[l];
        float dvx = vj.x - wvx[l], dvy = vj.y - wvy[l];
        float d2 = dpx * dpx + dpy * dpy;
        float sd2 = (d2 > 0.f) ? d2 : 1.f;
        float cdp = wc0[l] - wc2[l] / sd2;   // p0*A1 - p2*A3/sd2
        float cdv = wc1[l];                  // p1*A2
        float mx = (cdp * dpx + cdv * dvx) * f;
        float my = (cdp * dpy + cdv * dvy) * f;
        atomicAdd(&acc[2 * l + 0], mx);      // LDS atomic
        atomicAdd(&acc[2 * l + 1], my);
    }
    __syncthreads();
    for (int t = tid; t < 2 * wn; t += NT) out[2 * base + t] = acc[t];
}

// ---------------- fallback: baseline edge-parallel atomics ----------------
__global__ void boids_edge_kernel(const float* __restrict__ pos,
                                  const float* __restrict__ vel,
                                  const float* __restrict__ p_table,
                                  const float* __restrict__ field,
                                  const int* __restrict__ ptype,
                                  const int* __restrict__ dst_idx,
                                  const int* __restrict__ src_idx,
                                  float* __restrict__ out,
                                  int n_edges) {
    int e = blockIdx.x * blockDim.x + threadIdx.x;
    if (e >= n_edges) return;
    int i = dst_idx[e], j = src_idx[e];
    float2 pi = *reinterpret_cast<const float2*>(pos + 2 * i);
    float2 pj = *reinterpret_cast<const float2*>(pos + 2 * j);
    float2 vi = *reinterpret_cast<const float2*>(vel + 2 * i);
    float2 vj = *reinterpret_cast<const float2*>(vel + 2 * j);
    float dpx = pj.x - pi.x, dpy = pj.y - pi.y;
    float dvx = vj.x - vi.x, dvy = vj.y - vi.y;
    int t = ptype[i];
    float p0 = p_table[3 * t + 0], p1 = p_table[3 * t + 1], p2 = p_table[3 * t + 2];
    float d2 = dpx * dpx + dpy * dpy;
    float sd2 = (d2 > 0.0f) ? d2 : 1.0f;
    float cdp = p0 * BA1 - p2 * BA3 / sd2;
    float cdv = p1 * BA2;
    float f = field[j];
    atomicAdd(&out[2 * i + 0], (cdp * dpx + cdv * dvx) * f);
    atomicAdd(&out[2 * i + 1], (cdp * dpy + cdv * dvy) * f);
}

extern "C" void kernel_launch(void* const* d_in, const int* in_sizes, int n_in,
                              void* d_out, int out_size, void* d_ws, size_t ws_size,
                              hipStream_t stream) {
    const float* pos     = (const float*)d_in[0];   // [N,2]
    const float* vel     = (const float*)d_in[1];   // [N,2]
    const float* p_table = (const float*)d_in[2];   // [16,3]
    const float* field   = (const float*)d_in[3];   // [N,1]
    const int*   ptype   = (const int*)d_in[4];     // [N]
    const int*   eidx    = (const int*)d_in[5];     // [2,E]

    int N = in_sizes[0] / 2;
    int E = in_sizes[5] / 2;
    const int* dstI = eidx;
    const int* srcI = eidx + E;
    float* out = (float*)d_out;

    int NB   = (N + WIN - 1) / WIN;        // buckets
    int NBLK = (E + EPB - 1) / EPB;        // count/scatter blocks
    size_t M = (size_t)NB * NBLK;          // count-matrix entries
    int NCH  = (int)((M + SCAN_T - 1) / SCAN_T);

    // ws layout: pairs[E] uint2 | C[M] u32 | sums[NCH] u32
    size_t need = (size_t)E * sizeof(uint2) + M * 4 + (size_t)NCH * 4;
    bool ok = (ws_size >= need) && (NCH <= SCAN_T) && ((size_t)NB * 4 <= 48 * 1024);

    if (!ok) {
        hipMemsetAsync(out, 0, (size_t)out_size * sizeof(float), stream);
        int grid = (E + NT - 1) / NT;
        boids_edge_kernel<<<grid, NT, 0, stream>>>(pos, vel, p_table, field,
                                                   ptype, dstI, srcI, out, E);
        return;
    }

    uint2*    pairs = (uint2*)d_ws;
    unsigned* C     = (unsigned*)((char*)d_ws + (size_t)E * sizeof(uint2));
    unsigned* sums  = C + M;

    k_count  <<<NBLK, NT, (size_t)NB * 4, stream>>>(dstI, E, NB, NBLK, C);
    k_scan   <<<NCH, SCAN_T, 0, stream>>>(C, sums, (int)M);
    k_scan   <<<1,   SCAN_T, 0, stream>>>(sums, nullptr, NCH);
    k_scan_add<<<NCH, SCAN_T, 0, stream>>>(C, sums, (int)M);
    k_scatter<<<NBLK, NT, (size_t)NB * 4, stream>>>(dstI, srcI, E, NB, NBLK, C, pairs);
    k_accum  <<<NB, NT, 0, stream>>>(pos, vel, p_table, field, ptype,
                                     pairs, C, E, N, NB, NBLK, out);
}

// Round 3
// 161.415 us; speedup vs baseline: 3.9948x; 1.3233x over previous
//
#include <hip/hip_runtime.h>

// Boids ODE segment-sum, atomic-free counting-sort pipeline, v2:
//   pack kernel (node float4) -> count -> scan(3) -> scatter (u32 payload)
//   -> accum (NB x SPLIT blocks, LDS acc, coarse global atomics into out)

#define BA1 5e-06f
#define BA2 0.0005f
#define BA3 1e-08f

#define NT 256        // threads per block (all kernels except scan)
#define EPB 8192      // edges per count/scatter block
#define WIN 256       // receiver nodes per bucket
#define WSH 8         // log2(WIN)
#define SPLIT 8       // accum blocks per bucket
#define SCAN_T 1024   // scan block width

// ---------------- K0: pack node data {px,py,vx,vy} ----------------
__global__ void k_pack(const float* __restrict__ pos, const float* __restrict__ vel,
                       float4* __restrict__ node4, int N) {
    int i = blockIdx.x * blockDim.x + threadIdx.x;
    if (i >= N) return;
    float2 p = *reinterpret_cast<const float2*>(pos + 2 * i);
    float2 v = *reinterpret_cast<const float2*>(vel + 2 * i);
    node4[i] = make_float4(p.x, p.y, v.x, v.y);
}

// ---------------- K1: per-block bucket histogram ----------------
__global__ void k_count(const int* __restrict__ dst, int E, int NB, int NBLK,
                        unsigned* __restrict__ C) {
    extern __shared__ unsigned hist[];   // NB entries
    int blk = blockIdx.x, tid = threadIdx.x;
    for (int b = tid; b < NB; b += NT) hist[b] = 0u;
    __syncthreads();
    int s = blk * EPB, e = min(E, s + EPB);
    int k = s + 4 * tid;
    for (; k + 3 < e; k += 4 * NT) {
        int4 d = *reinterpret_cast<const int4*>(dst + k);
        atomicAdd(&hist[d.x >> WSH], 1u);
        atomicAdd(&hist[d.y >> WSH], 1u);
        atomicAdd(&hist[d.z >> WSH], 1u);
        atomicAdd(&hist[d.w >> WSH], 1u);
    }
    for (; k < e; ++k) atomicAdd(&hist[dst[k] >> WSH], 1u);
    __syncthreads();
    for (int b = tid; b < NB; b += NT) C[(size_t)b * NBLK + blk] = hist[b];
}

// ---------------- K2: exclusive scan (two-level) ----------------
__global__ void k_scan(unsigned* __restrict__ data, unsigned* __restrict__ sums, int M) {
    __shared__ unsigned tmp[SCAN_T];
    int tid = threadIdx.x;
    int gid = blockIdx.x * SCAN_T + tid;
    unsigned v = (gid < M) ? data[gid] : 0u;
    tmp[tid] = v;
    __syncthreads();
    for (int o = 1; o < SCAN_T; o <<= 1) {
        unsigned t = (tid >= o) ? tmp[tid - o] : 0u;
        __syncthreads();
        tmp[tid] += t;
        __syncthreads();
    }
    if (gid < M) data[gid] = tmp[tid] - v;                   // exclusive
    if (sums != nullptr && tid == SCAN_T - 1) sums[blockIdx.x] = tmp[tid];
}

__global__ void k_scan_add(unsigned* __restrict__ data,
                           const unsigned* __restrict__ sums, int M) {
    int gid = blockIdx.x * SCAN_T + threadIdx.x;
    if (gid < M) data[gid] += sums[blockIdx.x];
}

// ---------------- K3: scatter packed (l<<24)|src into bucket regions ----------------
__global__ void k_scatter(const int* __restrict__ dst, const int* __restrict__ src,
                          int E, int NB, int NBLK,
                          const unsigned* __restrict__ off,
                          unsigned* __restrict__ pk) {
    extern __shared__ unsigned cur[];    // NB cursors
    int blk = blockIdx.x, tid = threadIdx.x;
    for (int b = tid; b < NB; b += NT) cur[b] = off[(size_t)b * NBLK + blk];
    __syncthreads();
    int s = blk * EPB, e = min(E, s + EPB);
    int k = s + 4 * tid;
    for (; k + 3 < e; k += 4 * NT) {
        int4 d = *reinterpret_cast<const int4*>(dst + k);
        int4 j = *reinterpret_cast<const int4*>(src + k);
        unsigned p0 = atomicAdd(&cur[d.x >> WSH], 1u);
        pk[p0] = ((unsigned)(d.x & (WIN - 1)) << 24) | (unsigned)j.x;
        unsigned p1 = atomicAdd(&cur[d.y >> WSH], 1u);
        pk[p1] = ((unsigned)(d.y & (WIN - 1)) << 24) | (unsigned)j.y;
        unsigned p2 = atomicAdd(&cur[d.z >> WSH], 1u);
        pk[p2] = ((unsigned)(d.z & (WIN - 1)) << 24) | (unsigned)j.z;
        unsigned p3 = atomicAdd(&cur[d.w >> WSH], 1u);
        pk[p3] = ((unsigned)(d.w & (WIN - 1)) << 24) | (unsigned)j.w;
    }
    for (; k < e; ++k) {
        int d = dst[k];
        unsigned p = atomicAdd(&cur[d >> WSH], 1u);
        pk[p] = ((unsigned)(d & (WIN - 1)) << 24) | (unsigned)src[k];
    }
}

// ---------------- K4: per-(bucket,split) accumulate in LDS ----------------
__global__ void k_accum(const float4* __restrict__ node4,
                        const float* __restrict__ p_table,
                        const float* __restrict__ field,
                        const int* __restrict__ ptype,
                        const unsigned* __restrict__ pk,
                        const unsigned* __restrict__ off,
                        int E, int N, int NB, int NBLK,
                        float* __restrict__ out) {
    __shared__ float4 wnode[WIN];   // receiver pos/vel
    __shared__ float4 wcoef[WIN];   // {p0*A1, p1*A2, p2*A3, 0}
    __shared__ float  acc[2 * WIN];
    int b = blockIdx.x, tid = threadIdx.x;
    int base = b << WSH;
    int wn = min(N - base, WIN);

    if (tid < wn) {
        int g = base + tid;
        wnode[tid] = node4[g];
        int ty = ptype[g];
        wcoef[tid] = make_float4(p_table[3 * ty + 0] * BA1,
                                 p_table[3 * ty + 1] * BA2,
                                 p_table[3 * ty + 2] * BA3, 0.f);
    }
    acc[tid] = 0.f;
    acc[tid + WIN] = 0.f;
    __syncthreads();

    unsigned s = off[(size_t)b * NBLK];
    unsigned e = (b + 1 < NB) ? off[(size_t)(b + 1) * NBLK] : (unsigned)E;
    for (unsigned k = s + blockIdx.y * NT + tid; k < e; k += NT * SPLIT) {
        unsigned p = pk[k];
        int l = (int)(p >> 24);
        int j = (int)(p & 0xFFFFFFu);
        float4 w = wnode[l];
        float4 c = wcoef[l];
        float4 nj = node4[j];
        float  f  = field[j];
        float dpx = nj.x - w.x, dpy = nj.y - w.y;
        float dvx = nj.z - w.z, dvy = nj.w - w.w;
        float d2 = dpx * dpx + dpy * dpy;
        float sd2 = (d2 > 0.f) ? d2 : 1.f;
        float cdp = c.x - c.z / sd2;
        float mx = (cdp * dpx + c.y * dvx) * f;
        float my = (cdp * dpy + c.y * dvy) * f;
        atomicAdd(&acc[2 * l + 0], mx);      // LDS atomic
        atomicAdd(&acc[2 * l + 1], my);
    }
    __syncthreads();
    for (int t = tid; t < 2 * wn; t += NT) {
        float v = acc[t];
        if (v != 0.f || true) atomicAdd(&out[2 * base + t], v);
    }
}

// ---------------- fallback: baseline edge-parallel atomics ----------------
__global__ void boids_edge_kernel(const float* __restrict__ pos,
                                  const float* __restrict__ vel,
                                  const float* __restrict__ p_table,
                                  const float* __restrict__ field,
                                  const int* __restrict__ ptype,
                                  const int* __restrict__ dst_idx,
                                  const int* __restrict__ src_idx,
                                  float* __restrict__ out,
                                  int n_edges) {
    int e = blockIdx.x * blockDim.x + threadIdx.x;
    if (e >= n_edges) return;
    int i = dst_idx[e], j = src_idx[e];
    float2 pi = *reinterpret_cast<const float2*>(pos + 2 * i);
    float2 pj = *reinterpret_cast<const float2*>(pos + 2 * j);
    float2 vi = *reinterpret_cast<const float2*>(vel + 2 * i);
    float2 vj = *reinterpret_cast<const float2*>(vel + 2 * j);
    float dpx = pj.x - pi.x, dpy = pj.y - pi.y;
    float dvx = vj.x - vi.x, dvy = vj.y - vi.y;
    int t = ptype[i];
    float p0 = p_table[3 * t + 0], p1 = p_table[3 * t + 1], p2 = p_table[3 * t + 2];
    float d2 = dpx * dpx + dpy * dpy;
    float sd2 = (d2 > 0.0f) ? d2 : 1.0f;
    float cdp = p0 * BA1 - p2 * BA3 / sd2;
    float cdv = p1 * BA2;
    float f = field[j];
    atomicAdd(&out[2 * i + 0], (cdp * dpx + cdv * dvx) * f);
    atomicAdd(&out[2 * i + 1], (cdp * dpy + cdv * dvy) * f);
}

extern "C" void kernel_launch(void* const* d_in, const int* in_sizes, int n_in,
                              void* d_out, int out_size, void* d_ws, size_t ws_size,
                              hipStream_t stream) {
    const float* pos     = (const float*)d_in[0];   // [N,2]
    const float* vel     = (const float*)d_in[1];   // [N,2]
    const float* p_table = (const float*)d_in[2];   // [16,3]
    const float* field   = (const float*)d_in[3];   // [N,1]
    const int*   ptype   = (const int*)d_in[4];     // [N]
    const int*   eidx    = (const int*)d_in[5];     // [2,E]

    int N = in_sizes[0] / 2;
    int E = in_sizes[5] / 2;
    const int* dstI = eidx;
    const int* srcI = eidx + E;
    float* out = (float*)d_out;

    int NB   = (N + WIN - 1) >> WSH;       // buckets
    int NBLK = (E + EPB - 1) / EPB;        // count/scatter blocks
    size_t M = (size_t)NB * NBLK;          // count-matrix entries
    int NCH  = (int)((M + SCAN_T - 1) / SCAN_T);

    // ws layout: node4[N] float4 | pk[E] u32 | C[M] u32 | sums[NCH] u32
    size_t off_node = 0;
    size_t off_pk   = off_node + (size_t)N * sizeof(float4);
    size_t off_C    = off_pk + (size_t)E * 4;
    size_t off_sums = off_C + M * 4;
    size_t need     = off_sums + (size_t)NCH * 4;

    bool ok = (ws_size >= need) && (NCH <= SCAN_T) &&
              ((size_t)NB * 4 <= 48 * 1024) && (N <= (1 << 24)) && ((E & 3) == 0);

    if (!ok) {
        hipMemsetAsync(out, 0, (size_t)out_size * sizeof(float), stream);
        int grid = (E + NT - 1) / NT;
        boids_edge_kernel<<<grid, NT, 0, stream>>>(pos, vel, p_table, field,
                                                   ptype, dstI, srcI, out, E);
        return;
    }

    float4*   node4 = (float4*)((char*)d_ws + off_node);
    unsigned* pk    = (unsigned*)((char*)d_ws + off_pk);
    unsigned* C     = (unsigned*)((char*)d_ws + off_C);
    unsigned* sums  = (unsigned*)((char*)d_ws + off_sums);

    hipMemsetAsync(out, 0, (size_t)out_size * sizeof(float), stream);

    k_pack   <<<(N + NT - 1) / NT, NT, 0, stream>>>(pos, vel, node4, N);
    k_count  <<<NBLK, NT, (size_t)NB * 4, stream>>>(dstI, E, NB, NBLK, C);
    k_scan   <<<NCH, SCAN_T, 0, stream>>>(C, sums, (int)M);
    k_scan   <<<1,   SCAN_T, 0, stream>>>(sums, nullptr, NCH);
    k_scan_add<<<NCH, SCAN_T, 0, stream>>>(C, sums, (int)M);
    k_scatter<<<NBLK, NT, (size_t)NB * 4, stream>>>(dstI, srcI, E, NB, NBLK, C, pk);
    dim3 agrid(NB, SPLIT);
    k_accum  <<<agrid, NT, 0, stream>>>(node4, p_table, field, ptype,
                                        pk, C, E, N, NB, NBLK, out);
}

// Round 4
// 138.504 us; speedup vs baseline: 4.6556x; 1.1654x over previous
//
#include <hip/hip_runtime.h>

// Boids ODE segment-sum, atomic-free counting-sort pipeline, v3:
//   pack (node rec8 {p,v|f,c0,c1,c2}) -> count -> scan(3)
//   -> scatter (block-local LDS multisplit, coalesced segment writes)
//   -> accum (NB x SPLIT blocks, LDS acc, unroll-2 gather ILP)

#define BA1 5e-06f
#define BA2 0.0005f
#define BA3 1e-08f

#define NT 256        // threads per block
#define EPB 8192      // edges per count/scatter block
#define WIN 256       // receiver nodes per bucket
#define WSH 8         // log2(WIN)
#define SPLIT 8       // accum blocks per bucket
#define SCAN_T 1024   // scan block width
#define NBMAX 512     // max buckets supported by scatter LDS tables

// ---------------- K0: pack node record: rec4[2i]={px,py,vx,vy}, rec4[2i+1]={f,c0,c1,c2}
__global__ void k_pack(const float* __restrict__ pos, const float* __restrict__ vel,
                       const float* __restrict__ field, const float* __restrict__ p_table,
                       const int* __restrict__ ptype,
                       float4* __restrict__ rec4, int N) {
    int i = blockIdx.x * blockDim.x + threadIdx.x;
    if (i >= N) return;
    float2 p = *reinterpret_cast<const float2*>(pos + 2 * i);
    float2 v = *reinterpret_cast<const float2*>(vel + 2 * i);
    int ty = ptype[i];
    rec4[2 * i + 0] = make_float4(p.x, p.y, v.x, v.y);
    rec4[2 * i + 1] = make_float4(field[i],
                                  p_table[3 * ty + 0] * BA1,
                                  p_table[3 * ty + 1] * BA2,
                                  p_table[3 * ty + 2] * BA3);
}

// ---------------- K1: per-block bucket histogram ----------------
__global__ void k_count(const int* __restrict__ dst, int E, int NB, int NBLK,
                        unsigned* __restrict__ C) {
    __shared__ unsigned hist[NBMAX];
    int blk = blockIdx.x, tid = threadIdx.x;
    for (int b = tid; b < NBMAX; b += NT) hist[b] = 0u;
    __syncthreads();
    int s = blk * EPB, e = min(E, s + EPB);
    int k = s + 4 * tid;
    for (; k + 3 < e; k += 4 * NT) {
        int4 d = *reinterpret_cast<const int4*>(dst + k);
        atomicAdd(&hist[d.x >> WSH], 1u);
        atomicAdd(&hist[d.y >> WSH], 1u);
        atomicAdd(&hist[d.z >> WSH], 1u);
        atomicAdd(&hist[d.w >> WSH], 1u);
    }
    for (; k < e; ++k) atomicAdd(&hist[dst[k] >> WSH], 1u);
    __syncthreads();
    for (int b = tid; b < NB; b += NT) C[(size_t)b * NBLK + blk] = hist[b];
}

// ---------------- K2: exclusive scan (two-level) ----------------
__global__ void k_scan(unsigned* __restrict__ data, unsigned* __restrict__ sums, int M) {
    __shared__ unsigned tmp[SCAN_T];
    int tid = threadIdx.x;
    int gid = blockIdx.x * SCAN_T + tid;
    unsigned v = (gid < M) ? data[gid] : 0u;
    tmp[tid] = v;
    __syncthreads();
    for (int o = 1; o < SCAN_T; o <<= 1) {
        unsigned t = (tid >= o) ? tmp[tid - o] : 0u;
        __syncthreads();
        tmp[tid] += t;
        __syncthreads();
    }
    if (gid < M) data[gid] = tmp[tid] - v;                   // exclusive
    if (sums != nullptr && tid == SCAN_T - 1) sums[blockIdx.x] = tmp[tid];
}

__global__ void k_scan_add(unsigned* __restrict__ data,
                           const unsigned* __restrict__ sums, int M) {
    int gid = blockIdx.x * SCAN_T + threadIdx.x;
    if (gid < M) data[gid] += sums[blockIdx.x];
}

// ---------------- K3: block-local multisplit scatter ----------------
// Reorders the block's 8192 edges by bucket in LDS, then writes each bucket
// segment contiguously at its pre-scanned global offset (coalesced runs).
__global__ void __launch_bounds__(NT)
k_scatter(const int* __restrict__ dst, const int* __restrict__ src,
          int E, int NB, int NBLK,
          const unsigned* __restrict__ C,
          unsigned* __restrict__ pk) {
    __shared__ unsigned lh[NBMAX];         // counts -> inclusive scan
    __shared__ unsigned lofs[NBMAX];       // counts copy -> exclusive offsets
    __shared__ unsigned lcur[NBMAX];       // running cursors
    __shared__ unsigned gbase[NBMAX];      // global segment base per bucket
    __shared__ unsigned sbuf[EPB];         // locally sorted payloads
    __shared__ unsigned short sbkt[EPB];   // bucket id per sorted slot
    int blk = blockIdx.x, tid = threadIdx.x;
    int s = blk * EPB, e = min(E, s + EPB);

    for (int b = tid; b < NBMAX; b += NT) lh[b] = 0u;
    __syncthreads();

    // pass 1: local histogram
    int k = s + 4 * tid;
    for (; k + 3 < e; k += 4 * NT) {
        int4 d = *reinterpret_cast<const int4*>(dst + k);
        atomicAdd(&lh[d.x >> WSH], 1u);
        atomicAdd(&lh[d.y >> WSH], 1u);
        atomicAdd(&lh[d.z >> WSH], 1u);
        atomicAdd(&lh[d.w >> WSH], 1u);
    }
    for (; k < e; ++k) atomicAdd(&lh[dst[k] >> WSH], 1u);
    __syncthreads();

    // preload global bases + keep a copy of counts
    for (int b = tid; b < NBMAX; b += NT) {
        if (b < NB) gbase[b] = C[(size_t)b * NBLK + blk];
        lofs[b] = lh[b];
    }
    __syncthreads();

    // inclusive Hillis-Steele scan over NBMAX entries (2 per thread)
    for (int o = 1; o < NBMAX; o <<= 1) {
        unsigned v0 = (tid >= o) ? lh[tid - o] : 0u;
        unsigned v1 = (tid + NT >= o) ? lh[tid + NT - o] : 0u;
        __syncthreads();
        lh[tid] += v0;
        lh[tid + NT] += v1;
        __syncthreads();
    }
    // exclusive offsets + cursors
    for (int b = tid; b < NBMAX; b += NT) {
        unsigned ex = lh[b] - lofs[b];
        lofs[b] = ex;
        lcur[b] = ex;
    }
    __syncthreads();

    // pass 2: place payloads into LDS, grouped by bucket
    k = s + 4 * tid;
    for (; k + 3 < e; k += 4 * NT) {
        int4 d = *reinterpret_cast<const int4*>(dst + k);
        int4 j = *reinterpret_cast<const int4*>(src + k);
        int b0 = d.x >> WSH; unsigned r0 = atomicAdd(&lcur[b0], 1u);
        sbuf[r0] = ((unsigned)(d.x & (WIN - 1)) << 24) | (unsigned)j.x; sbkt[r0] = (unsigned short)b0;
        int b1 = d.y >> WSH; unsigned r1 = atomicAdd(&lcur[b1], 1u);
        sbuf[r1] = ((unsigned)(d.y & (WIN - 1)) << 24) | (unsigned)j.y; sbkt[r1] = (unsigned short)b1;
        int b2 = d.z >> WSH; unsigned r2 = atomicAdd(&lcur[b2], 1u);
        sbuf[r2] = ((unsigned)(d.z & (WIN - 1)) << 24) | (unsigned)j.z; sbkt[r2] = (unsigned short)b2;
        int b3 = d.w >> WSH; unsigned r3 = atomicAdd(&lcur[b3], 1u);
        sbuf[r3] = ((unsigned)(d.w & (WIN - 1)) << 24) | (unsigned)j.w; sbkt[r3] = (unsigned short)b3;
    }
    for (; k < e; ++k) {
        int d = dst[k];
        int b = d >> WSH; unsigned r = atomicAdd(&lcur[b], 1u);
        sbuf[r] = ((unsigned)(d & (WIN - 1)) << 24) | (unsigned)src[k]; sbkt[r] = (unsigned short)b;
    }
    __syncthreads();

    // write phase: consecutive slots in a bucket -> consecutive global addrs
    int ne = e - s;
    for (int t = tid; t < ne; t += NT) {
        unsigned b = sbkt[t];
        pk[gbase[b] + ((unsigned)t - lofs[b])] = sbuf[t];
    }
}

// ---------------- K4: per-(bucket,split) accumulate in LDS, unroll-2 ----------------
__global__ void __launch_bounds__(NT)
k_accum(const float4* __restrict__ rec4,
        const unsigned* __restrict__ pk,
        const unsigned* __restrict__ off,
        int E, int N, int NB, int NBLK,
        float* __restrict__ out) {
    __shared__ float4 wnode[WIN];   // receiver pos/vel
    __shared__ float4 wcoef[WIN];   // {f_i(unused), c0, c1, c2}
    __shared__ float  acc[2 * WIN];
    int b = blockIdx.x, tid = threadIdx.x;
    int base = b << WSH;
    int wn = min(N - base, WIN);

    if (tid < wn) {
        int g = base + tid;
        wnode[tid] = rec4[2 * g + 0];
        wcoef[tid] = rec4[2 * g + 1];
    }
    acc[tid] = 0.f;
    acc[tid + WIN] = 0.f;
    __syncthreads();

    unsigned s = off[(size_t)b * NBLK];
    unsigned e = (b + 1 < NB) ? off[(size_t)(b + 1) * NBLK] : (unsigned)E;
    const unsigned ST = NT * SPLIT;
    unsigned k = s + blockIdx.y * NT + tid;

#define EDGE_BODY(KK)                                                          \
    {                                                                          \
        unsigned p_ = pk[KK];                                                  \
        int l_ = (int)(p_ >> 24);                                              \
        int j_ = (int)(p_ & 0xFFFFFFu);                                        \
        float4 nj_ = rec4[2 * j_ + 0];                                         \
        float  f_  = reinterpret_cast<const float*>(rec4)[8 * j_ + 4];         \
        float4 w_ = wnode[l_];                                                 \
        float4 c_ = wcoef[l_];                                                 \
        float dpx_ = nj_.x - w_.x, dpy_ = nj_.y - w_.y;                        \
        float dvx_ = nj_.z - w_.z, dvy_ = nj_.w - w_.w;                        \
        float d2_ = dpx_ * dpx_ + dpy_ * dpy_;                                 \
        float sd2_ = (d2_ > 0.f) ? d2_ : 1.f;                                  \
        float cdp_ = c_.y - c_.w / sd2_;                                       \
        float mx_ = (cdp_ * dpx_ + c_.z * dvx_) * f_;                          \
        float my_ = (cdp_ * dpy_ + c_.z * dvy_) * f_;                          \
        atomicAdd(&acc[2 * l_ + 0], mx_);                                      \
        atomicAdd(&acc[2 * l_ + 1], my_);                                      \
    }

    while (k + ST < e) {      // both k and k+ST valid
        EDGE_BODY(k);
        EDGE_BODY(k + ST);
        k += 2 * ST;
    }
    if (k < e) EDGE_BODY(k);
#undef EDGE_BODY

    __syncthreads();
    for (int t = tid; t < 2 * wn; t += NT) {
        atomicAdd(&out[2 * base + t], acc[t]);
    }
}

// ---------------- fallback: baseline edge-parallel atomics ----------------
__global__ void boids_edge_kernel(const float* __restrict__ pos,
                                  const float* __restrict__ vel,
                                  const float* __restrict__ p_table,
                                  const float* __restrict__ field,
                                  const int* __restrict__ ptype,
                                  const int* __restrict__ dst_idx,
                                  const int* __restrict__ src_idx,
                                  float* __restrict__ out,
                                  int n_edges) {
    int e = blockIdx.x * blockDim.x + threadIdx.x;
    if (e >= n_edges) return;
    int i = dst_idx[e], j = src_idx[e];
    float2 pi = *reinterpret_cast<const float2*>(pos + 2 * i);
    float2 pj = *reinterpret_cast<const float2*>(pos + 2 * j);
    float2 vi = *reinterpret_cast<const float2*>(vel + 2 * i);
    float2 vj = *reinterpret_cast<const float2*>(vel + 2 * j);
    float dpx = pj.x - pi.x, dpy = pj.y - pi.y;
    float dvx = vj.x - vi.x, dvy = vj.y - vi.y;
    int t = ptype[i];
    float p0 = p_table[3 * t + 0], p1 = p_table[3 * t + 1], p2 = p_table[3 * t + 2];
    float d2 = dpx * dpx + dpy * dpy;
    float sd2 = (d2 > 0.0f) ? d2 : 1.0f;
    float cdp = p0 * BA1 - p2 * BA3 / sd2;
    float cdv = p1 * BA2;
    float f = field[j];
    atomicAdd(&out[2 * i + 0], (cdp * dpx + cdv * dvx) * f);
    atomicAdd(&out[2 * i + 1], (cdp * dpy + cdv * dvy) * f);
}

extern "C" void kernel_launch(void* const* d_in, const int* in_sizes, int n_in,
                              void* d_out, int out_size, void* d_ws, size_t ws_size,
                              hipStream_t stream) {
    const float* pos     = (const float*)d_in[0];   // [N,2]
    const float* vel     = (const float*)d_in[1];   // [N,2]
    const float* p_table = (const float*)d_in[2];   // [16,3]
    const float* field   = (const float*)d_in[3];   // [N,1]
    const int*   ptype   = (const int*)d_in[4];     // [N]
    const int*   eidx    = (const int*)d_in[5];     // [2,E]

    int N = in_sizes[0] / 2;
    int E = in_sizes[5] / 2;
    const int* dstI = eidx;
    const int* srcI = eidx + E;
    float* out = (float*)d_out;

    int NB   = (N + WIN - 1) >> WSH;       // buckets
    int NBLK = (E + EPB - 1) / EPB;        // count/scatter blocks
    size_t M = (size_t)NB * NBLK;          // count-matrix entries
    int NCH  = (int)((M + SCAN_T - 1) / SCAN_T);

    // ws layout: rec4[2N] float4 | pk[E] u32 | C[M] u32 | sums[NCH] u32
    size_t off_rec  = 0;
    size_t off_pk   = off_rec + (size_t)N * 2 * sizeof(float4);
    size_t off_C    = off_pk + (size_t)E * 4;
    size_t off_sums = off_C + M * 4;
    size_t need     = off_sums + (size_t)NCH * 4;

    bool ok = (ws_size >= need) && (NCH <= SCAN_T) && (NB <= NBMAX) &&
              (N <= (1 << 24)) && ((E & 3) == 0);

    if (!ok) {
        hipMemsetAsync(out, 0, (size_t)out_size * sizeof(float), stream);
        int grid = (E + NT - 1) / NT;
        boids_edge_kernel<<<grid, NT, 0, stream>>>(pos, vel, p_table, field,
                                                   ptype, dstI, srcI, out, E);
        return;
    }

    float4*   rec4 = (float4*)((char*)d_ws + off_rec);
    unsigned* pk   = (unsigned*)((char*)d_ws + off_pk);
    unsigned* C    = (unsigned*)((char*)d_ws + off_C);
    unsigned* sums = (unsigned*)((char*)d_ws + off_sums);

    hipMemsetAsync(out, 0, (size_t)out_size * sizeof(float), stream);

    k_pack   <<<(N + NT - 1) / NT, NT, 0, stream>>>(pos, vel, field, p_table,
                                                    ptype, rec4, N);
    k_count  <<<NBLK, NT, 0, stream>>>(dstI, E, NB, NBLK, C);
    k_scan   <<<NCH, SCAN_T, 0, stream>>>(C, sums, (int)M);
    k_scan   <<<1,   SCAN_T, 0, stream>>>(sums, nullptr, NCH);
    k_scan_add<<<NCH, SCAN_T, 0, stream>>>(C, sums, (int)M);
    k_scatter<<<NBLK, NT, 0, stream>>>(dstI, srcI, E, NB, NBLK, C, pk);
    dim3 agrid(NB, SPLIT);
    k_accum  <<<agrid, NT, 0, stream>>>(rec4, pk, C, E, N, NB, NBLK, out);
}